// Round 5
// baseline (213.774 us; speedup 1.0000x reference)
//
#include <hip/hip_runtime.h>
#include <hip/hip_bf16.h>
#include <hip/hip_cooperative_groups.h>

namespace cg = cooperative_groups;

// Live computation only (GNN layers are dead code in the reference):
//   hg[b] = [mean(h_comp|g==b), mean2(h_port|g==b), mean(h_net|g==b)]  -> [64,4]
//   out = relu(relu(hg@Wc1+bc1)@Wc2+bc2)@Wc3+bc3                        -> [64,10]
//
// Single cooperative kernel, 1024 blocks x 256 threads (= 4 blocks/CU, all
// co-resident per __launch_bounds__(256,4)).
//   Phase 1: segmented sums into LDS bins; each block stores its private
//            64x{s0,s1,cnt} slot (fully written -> no zero-init, no atomics).
//   grid.sync()  (device-scope fence: slot stores visible cross-XCD)
//   Phase 2: blocks 0..63 gather all slots for their graph (coalesced) and
//            run the tiny MLP; remaining blocks exit.
// Fallback: if the cooperative launch is rejected, run the proven R4
// two-kernel path (same math, same ws layout).

#define NGRAPH 64
#define NB_COMP 120
#define NB_PORT 723
#define NB_NET  181
#define NSLOT (NB_COMP + NB_PORT + NB_NET)  // 1024

// ws layout: float4 slot[g][s] = {s0, s1, cnt, 0}, g in [0,64), s in [0,1024)

template <int NF>
__device__ void reduce_type(const float* __restrict__ h, const int* __restrict__ gid, int n,
                            float (*bins)[NGRAPH][4],
                            int nblocks, int bid) {
    int nv = (n + 3) >> 2;  // vec4 groups
    int per = (nv + nblocks - 1) / nblocks;
    int start = bid * per;
    int end = min(nv, start + per);
    int set = threadIdx.x & 3;

    int cur = -1;
    float s0 = 0.f, s1 = 0.f, cnt = 0.f;

    for (int iv = start + (int)threadIdx.x; iv < end; iv += (int)blockDim.x) {
        int i = iv * 4;
        int g[4];
        float v0[4], v1[4];
        if (i + 3 < n) {
            int4 g4 = ((const int4*)gid)[iv];
            g[0] = g4.x; g[1] = g4.y; g[2] = g4.z; g[3] = g4.w;
            if (NF == 1) {
                float4 hv = ((const float4*)h)[iv];
                v0[0] = hv.x; v0[1] = hv.y; v0[2] = hv.z; v0[3] = hv.w;
            } else {
                float4 ha = ((const float4*)h)[iv * 2];
                float4 hb = ((const float4*)h)[iv * 2 + 1];
                v0[0] = ha.x; v1[0] = ha.y; v0[1] = ha.z; v1[1] = ha.w;
                v0[2] = hb.x; v1[2] = hb.y; v0[3] = hb.z; v1[3] = hb.w;
            }
        } else {
#pragma unroll
            for (int t = 0; t < 4; ++t) {
                if (i + t < n) {
                    g[t] = gid[i + t];
                    if (NF == 1) { v0[t] = h[i + t]; }
                    else { v0[t] = h[(i + t) * 2]; v1[t] = h[(i + t) * 2 + 1]; }
                } else {
                    g[t] = -2;  // sentinel: skip
                    v0[t] = 0.f; v1[t] = 0.f;
                }
            }
        }
#pragma unroll
        for (int t = 0; t < 4; ++t) {
            if (g[t] == -2) continue;
            if (g[t] != cur) {
                if (cur >= 0) {
                    atomicAdd(&bins[set][cur][0], s0);
                    if (NF == 2) atomicAdd(&bins[set][cur][1], s1);
                    atomicAdd(&bins[set][cur][2], cnt);
                }
                cur = g[t]; s0 = 0.f; s1 = 0.f; cnt = 0.f;
            }
            s0 += v0[t];
            if (NF == 2) s1 += v1[t];
            cnt += 1.f;
        }
    }
    if (cur >= 0) {
        atomicAdd(&bins[set][cur][0], s0);
        if (NF == 2) atomicAdd(&bins[set][cur][1], s1);
        atomicAdd(&bins[set][cur][2], cnt);
    }
}

// ---- Phase-1 body (shared by fused + fallback kernels) ----
__device__ __forceinline__ void phase1(
    const float* __restrict__ h_comp, const float* __restrict__ h_port,
    const float* __restrict__ h_net,
    const int* __restrict__ gid_comp, const int* __restrict__ gid_port,
    const int* __restrict__ gid_net,
    int n_comp, int n_port, int n_net,
    float4* __restrict__ ws4, float (*bins)[NGRAPH][4]) {
    int tid = threadIdx.x;
    int bid = blockIdx.x;

    for (int i = tid; i < 4 * NGRAPH * 4; i += 256) ((float*)bins)[i] = 0.f;
    __syncthreads();

    if (bid < NB_COMP) {
        reduce_type<1>(h_comp, gid_comp, n_comp, bins, NB_COMP, bid);
    } else if (bid < NB_COMP + NB_PORT) {
        reduce_type<2>(h_port, gid_port, n_port, bins, NB_PORT, bid - NB_COMP);
    } else {
        reduce_type<1>(h_net, gid_net, n_net, bins, NB_NET, bid - NB_COMP - NB_PORT);
    }
    __syncthreads();

    if (tid < NGRAPH) {
        float s0 = bins[0][tid][0] + bins[1][tid][0] + bins[2][tid][0] + bins[3][tid][0];
        float s1 = bins[0][tid][1] + bins[1][tid][1] + bins[2][tid][1] + bins[3][tid][1];
        float c  = bins[0][tid][2] + bins[1][tid][2] + bins[2][tid][2] + bins[3][tid][2];
        ws4[(size_t)tid * NSLOT + bid] = make_float4(s0, s1, c, 0.f);
    }
}

// ---- Phase-2 body: MLP for graph g (needs 256 threads) ----
__device__ __forceinline__ void phase2(
    int g, const float4* __restrict__ ws4,
    const float* __restrict__ Wc1, const float* __restrict__ bc1,
    const float* __restrict__ Wc2, const float* __restrict__ bc2,
    const float* __restrict__ Wc3, const float* __restrict__ bc3,
    float* __restrict__ out,
    float (*wred)[8], float* hgs, float* h1, float (*part)[128],
    float* h2, float (*l3)[12]) {
    int tid = threadIdx.x;

    // Gather + reduce this graph's slots (coalesced 16 KB)
    float cs = 0.f, cc = 0.f, p0 = 0.f, p1 = 0.f, pc = 0.f, ns = 0.f, nc = 0.f;
    for (int s = tid; s < NSLOT; s += 256) {
        float4 v = ws4[(size_t)g * NSLOT + s];
        if (s < NB_COMP) { cs += v.x; cc += v.z; }
        else if (s < NB_COMP + NB_PORT) { p0 += v.x; p1 += v.y; pc += v.z; }
        else { ns += v.x; nc += v.z; }
    }
#pragma unroll
    for (int off = 32; off > 0; off >>= 1) {
        cs += __shfl_down(cs, off); cc += __shfl_down(cc, off);
        p0 += __shfl_down(p0, off); p1 += __shfl_down(p1, off);
        pc += __shfl_down(pc, off); ns += __shfl_down(ns, off);
        nc += __shfl_down(nc, off);
    }
    int wave = tid >> 6;
    if ((tid & 63) == 0) {
        wred[wave][0] = cs; wred[wave][1] = cc; wred[wave][2] = p0; wred[wave][3] = p1;
        wred[wave][4] = pc; wred[wave][5] = ns; wred[wave][6] = nc;
    }
    __syncthreads();
    if (tid == 0) {
        float t0 = wred[0][0] + wred[1][0] + wred[2][0] + wred[3][0];
        float t1 = wred[0][1] + wred[1][1] + wred[2][1] + wred[3][1];
        float t2 = wred[0][2] + wred[1][2] + wred[2][2] + wred[3][2];
        float t3 = wred[0][3] + wred[1][3] + wred[2][3] + wred[3][3];
        float t4 = wred[0][4] + wred[1][4] + wred[2][4] + wred[3][4];
        float t5 = wred[0][5] + wred[1][5] + wred[2][5] + wred[3][5];
        float t6 = wred[0][6] + wred[1][6] + wred[2][6] + wred[3][6];
        hgs[0] = t0 / fmaxf(t1, 1.f);
        hgs[1] = t2 / fmaxf(t4, 1.f);
        hgs[2] = t3 / fmaxf(t4, 1.f);
        hgs[3] = t5 / fmaxf(t6, 1.f);
    }
    __syncthreads();

    // Layer 1: [4] @ [4,128]
    if (tid < 128) {
        float v = hgs[0] * Wc1[tid] + hgs[1] * Wc1[128 + tid] +
                  hgs[2] * Wc1[256 + tid] + hgs[3] * Wc1[384 + tid] + bc1[tid];
        h1[tid] = fmaxf(v, 0.f);
    }
    __syncthreads();

    // Layer 2: [128] @ [128,128], split-k over 2 half-waves
    {
        int j = tid & 127;
        int h = tid >> 7;
        float acc = 0.f;
#pragma unroll
        for (int kk = 0; kk < 64; kk += 4) {
            int k = h * 64 + kk;
            float4 hh = *(const float4*)&h1[k];
            acc += hh.x * Wc2[(k + 0) * 128 + j] + hh.y * Wc2[(k + 1) * 128 + j] +
                   hh.z * Wc2[(k + 2) * 128 + j] + hh.w * Wc2[(k + 3) * 128 + j];
        }
        part[h][j] = acc;
    }
    __syncthreads();
    if (tid < 128) h2[tid] = fmaxf(part[0][tid] + part[1][tid] + bc2[tid], 0.f);
    __syncthreads();

    // Layer 3: [128] @ [128,10], split-k over 16 segments of 8
    if (tid < 160) {
        int c = tid % 10;
        int seg = tid / 10;
        float a = 0.f;
#pragma unroll
        for (int k = seg * 8; k < seg * 8 + 8; ++k) a += h2[k] * Wc3[k * 10 + c];
        l3[seg][c] = a;
    }
    __syncthreads();
    if (tid < 10) {
        float a = bc3[tid];
#pragma unroll
        for (int s = 0; s < 16; ++s) a += l3[s][tid];
        out[g * 10 + tid] = a;
    }
}

__global__ __launch_bounds__(256, 4) void fused_kernel(
    const float* __restrict__ h_comp, const float* __restrict__ h_port,
    const float* __restrict__ h_net,
    const int* __restrict__ gid_comp, const int* __restrict__ gid_port,
    const int* __restrict__ gid_net,
    int n_comp, int n_port, int n_net,
    const float* __restrict__ Wc1, const float* __restrict__ bc1,
    const float* __restrict__ Wc2, const float* __restrict__ bc2,
    const float* __restrict__ Wc3, const float* __restrict__ bc3,
    float4* __restrict__ ws4, float* __restrict__ out) {
    __shared__ float bins[4][NGRAPH][4];
    __shared__ float wred[4][8];
    __shared__ float hgs[4];
    __shared__ float h1[128];
    __shared__ float part[2][128];
    __shared__ float h2[128];
    __shared__ float l3[16][12];

    phase1(h_comp, h_port, h_net, gid_comp, gid_port, gid_net,
           n_comp, n_port, n_net, ws4, bins);

    cg::this_grid().sync();

    if (blockIdx.x < NGRAPH) {
        phase2(blockIdx.x, ws4, Wc1, bc1, Wc2, bc2, Wc3, bc3, out,
               wred, hgs, h1, part, h2, l3);
    }
}

// ---- Fallback path (R4 proven): two plain kernels ----
__global__ __launch_bounds__(256) void reduce_kernel(
    const float* __restrict__ h_comp, const float* __restrict__ h_port,
    const float* __restrict__ h_net,
    const int* __restrict__ gid_comp, const int* __restrict__ gid_port,
    const int* __restrict__ gid_net,
    int n_comp, int n_port, int n_net,
    float4* __restrict__ ws4) {
    __shared__ float bins[4][NGRAPH][4];
    phase1(h_comp, h_port, h_net, gid_comp, gid_port, gid_net,
           n_comp, n_port, n_net, ws4, bins);
}

__global__ __launch_bounds__(256) void mlp_kernel(
    const float4* __restrict__ ws4,
    const float* __restrict__ Wc1, const float* __restrict__ bc1,
    const float* __restrict__ Wc2, const float* __restrict__ bc2,
    const float* __restrict__ Wc3, const float* __restrict__ bc3,
    float* __restrict__ out) {
    __shared__ float wred[4][8];
    __shared__ float hgs[4];
    __shared__ float h1[128];
    __shared__ float part[2][128];
    __shared__ float h2[128];
    __shared__ float l3[16][12];
    phase2(blockIdx.x, ws4, Wc1, bc1, Wc2, bc2, Wc3, bc3, out,
           wred, hgs, h1, part, h2, l3);
}

extern "C" void kernel_launch(void* const* d_in, const int* in_sizes, int n_in,
                              void* d_out, int out_size, void* d_ws, size_t ws_size,
                              hipStream_t stream) {
    const float* h_comp = (const float*)d_in[0];
    const float* h_port = (const float*)d_in[1];
    const float* h_net  = (const float*)d_in[2];
    // d_in[3..6]: edge arrays — dead code in the reference, unused.
    const int* gid_comp = (const int*)d_in[7];
    const int* gid_port = (const int*)d_in[8];
    const int* gid_net  = (const int*)d_in[9];
    // d_in[10..21]: GraphConv weights — dead code, unused.
    const float* Wc1 = (const float*)d_in[22];
    const float* bc1 = (const float*)d_in[23];
    const float* Wc2 = (const float*)d_in[24];
    const float* bc2 = (const float*)d_in[25];
    const float* Wc3 = (const float*)d_in[26];
    const float* bc3 = (const float*)d_in[27];

    int n_comp = in_sizes[0];       // 100000 (dim 1)
    int n_port = in_sizes[1] / 2;   // 400000 (dim 2)
    int n_net  = in_sizes[2];       // 150000 (dim 1)

    float4* ws4 = (float4*)d_ws;
    float* out = (float*)d_out;

    void* args[] = {
        (void*)&h_comp, (void*)&h_port, (void*)&h_net,
        (void*)&gid_comp, (void*)&gid_port, (void*)&gid_net,
        (void*)&n_comp, (void*)&n_port, (void*)&n_net,
        (void*)&Wc1, (void*)&bc1, (void*)&Wc2, (void*)&bc2,
        (void*)&Wc3, (void*)&bc3, (void*)&ws4, (void*)&out,
    };
    hipError_t err = hipLaunchCooperativeKernel(
        (const void*)fused_kernel, dim3(NSLOT), dim3(256), args, 0, stream);

    if (err != hipSuccess) {
        // Deterministic fallback: proven R4 two-kernel path.
        reduce_kernel<<<NSLOT, 256, 0, stream>>>(
            h_comp, h_port, h_net, gid_comp, gid_port, gid_net,
            n_comp, n_port, n_net, ws4);
        mlp_kernel<<<NGRAPH, 256, 0, stream>>>(ws4, Wc1, bc1, Wc2, bc2, Wc3, bc3, out);
    }
}

// Round 6
// 116.245 us; speedup vs baseline: 1.8390x; 1.8390x over previous
//
#include <hip/hip_runtime.h>
#include <hip/hip_bf16.h>

// Live computation only (GNN layers are dead code in the reference):
//   hg[b] = [mean(h_comp|g==b), mean2(h_port|g==b), mean(h_net|g==b)]  -> [64,4]
//   out = relu(relu(hg@Wc1+bc1)@Wc2+bc2)@Wc3+bc3                        -> [64,10]
//
// Two kernels (R4 structure — cooperative grid.sync() cost 60+us in R5, a
// kernel boundary is cheaper), no memset, no global atomics:
//   K1 (1024 blocks): segmented sums into LDS bins; each block stores its
//      64x{s0,s1,cnt} bins to a PRIVATE ws slot (fully written -> no zero-init).
//      FAST PATH: gid is sorted, so blocks whose slice spans a single graph
//      (gid[first]==gid[last], ~90% of blocks) skip ALL per-element gid loads.
//   K2 (64 blocks, one per graph): gather all slots for graph g (coalesced),
//      block-reduce, then run the tiny MLP.
// Kernel boundary provides cross-XCD visibility of the slot stores.

#define NGRAPH 64
#define NB_COMP 120
#define NB_PORT 723
#define NB_NET  181
#define NSLOT (NB_COMP + NB_PORT + NB_NET)  // 1024

// ws layout: float4 slot[g][s] = {s0, s1, cnt, 0}, g in [0,64), s in [0,1024)

template <int NF>
__device__ void reduce_type(const float* __restrict__ h, const int* __restrict__ gid, int n,
                            float (*bins)[NGRAPH][4],
                            int nblocks, int bid) {
    int nv = (n + 3) >> 2;  // vec4 groups
    int per = (nv + nblocks - 1) / nblocks;
    int start = bid * per;
    int end = min(nv, start + per);
    int set = threadIdx.x & 3;

    int first = start * 4;
    int last = min(end * 4, n) - 1;
    if (first > last) return;  // empty slice

    int g_lo = gid[first];
    int g_hi = gid[last];

    if (g_lo == g_hi) {
        // ---- FAST PATH: whole slice belongs to graph g_lo; no gid loads ----
        float s0 = 0.f, s1 = 0.f, cnt = 0.f;
        for (int iv = start + (int)threadIdx.x; iv < end; iv += (int)blockDim.x) {
            int i = iv * 4;
            if (i + 3 < n) {
                if (NF == 1) {
                    float4 hv = ((const float4*)h)[iv];
                    s0 += (hv.x + hv.y) + (hv.z + hv.w);
                } else {
                    float4 ha = ((const float4*)h)[iv * 2];
                    float4 hb = ((const float4*)h)[iv * 2 + 1];
                    s0 += ha.x + ha.z + hb.x + hb.z;
                    s1 += ha.y + ha.w + hb.y + hb.w;
                }
                cnt += 4.f;
            } else {
                for (int t = 0; t < 4 && i + t < n; ++t) {
                    if (NF == 1) { s0 += h[i + t]; }
                    else { s0 += h[(i + t) * 2]; s1 += h[(i + t) * 2 + 1]; }
                    cnt += 1.f;
                }
            }
        }
        // wave reduce (64 lanes), one LDS atomic per wave
#pragma unroll
        for (int off = 32; off > 0; off >>= 1) {
            s0 += __shfl_down(s0, off);
            if (NF == 2) s1 += __shfl_down(s1, off);
            cnt += __shfl_down(cnt, off);
        }
        if ((threadIdx.x & 63) == 0) {
            int wset = threadIdx.x >> 6;
            atomicAdd(&bins[wset][g_lo][0], s0);
            if (NF == 2) atomicAdd(&bins[wset][g_lo][1], s1);
            atomicAdd(&bins[wset][g_lo][2], cnt);
        }
        return;
    }

    // ---- SLOW PATH: slice straddles graph boundaries ----
    int cur = -1;
    float s0 = 0.f, s1 = 0.f, cnt = 0.f;

    for (int iv = start + (int)threadIdx.x; iv < end; iv += (int)blockDim.x) {
        int i = iv * 4;
        int g[4];
        float v0[4], v1[4];
        if (i + 3 < n) {
            int4 g4 = ((const int4*)gid)[iv];
            g[0] = g4.x; g[1] = g4.y; g[2] = g4.z; g[3] = g4.w;
            if (NF == 1) {
                float4 hv = ((const float4*)h)[iv];
                v0[0] = hv.x; v0[1] = hv.y; v0[2] = hv.z; v0[3] = hv.w;
            } else {
                float4 ha = ((const float4*)h)[iv * 2];
                float4 hb = ((const float4*)h)[iv * 2 + 1];
                v0[0] = ha.x; v1[0] = ha.y; v0[1] = ha.z; v1[1] = ha.w;
                v0[2] = hb.x; v1[2] = hb.y; v0[3] = hb.z; v1[3] = hb.w;
            }
        } else {
#pragma unroll
            for (int t = 0; t < 4; ++t) {
                if (i + t < n) {
                    g[t] = gid[i + t];
                    if (NF == 1) { v0[t] = h[i + t]; }
                    else { v0[t] = h[(i + t) * 2]; v1[t] = h[(i + t) * 2 + 1]; }
                } else {
                    g[t] = -2;  // sentinel: skip
                    v0[t] = 0.f; v1[t] = 0.f;
                }
            }
        }
#pragma unroll
        for (int t = 0; t < 4; ++t) {
            if (g[t] == -2) continue;
            if (g[t] != cur) {
                if (cur >= 0) {
                    atomicAdd(&bins[set][cur][0], s0);
                    if (NF == 2) atomicAdd(&bins[set][cur][1], s1);
                    atomicAdd(&bins[set][cur][2], cnt);
                }
                cur = g[t]; s0 = 0.f; s1 = 0.f; cnt = 0.f;
            }
            s0 += v0[t];
            if (NF == 2) s1 += v1[t];
            cnt += 1.f;
        }
    }
    if (cur >= 0) {
        atomicAdd(&bins[set][cur][0], s0);
        if (NF == 2) atomicAdd(&bins[set][cur][1], s1);
        atomicAdd(&bins[set][cur][2], cnt);
    }
}

__global__ __launch_bounds__(256) void reduce_kernel(
    const float* __restrict__ h_comp, const float* __restrict__ h_port,
    const float* __restrict__ h_net,
    const int* __restrict__ gid_comp, const int* __restrict__ gid_port,
    const int* __restrict__ gid_net,
    int n_comp, int n_port, int n_net,
    float4* __restrict__ ws4) {
    __shared__ float bins[4][NGRAPH][4];  // {s0, s1, cnt, pad} x 4 replica sets
    int tid = threadIdx.x;
    int bid = blockIdx.x;

    for (int i = tid; i < 4 * NGRAPH * 4; i += 256) ((float*)bins)[i] = 0.f;
    __syncthreads();

    if (bid < NB_COMP) {
        reduce_type<1>(h_comp, gid_comp, n_comp, bins, NB_COMP, bid);
    } else if (bid < NB_COMP + NB_PORT) {
        reduce_type<2>(h_port, gid_port, n_port, bins, NB_PORT, bid - NB_COMP);
    } else {
        reduce_type<1>(h_net, gid_net, n_net, bins, NB_NET, bid - NB_COMP - NB_PORT);
    }
    __syncthreads();

    // Store this block's 64-graph bins to its private slot (fully written).
    if (tid < NGRAPH) {
        float s0 = bins[0][tid][0] + bins[1][tid][0] + bins[2][tid][0] + bins[3][tid][0];
        float s1 = bins[0][tid][1] + bins[1][tid][1] + bins[2][tid][1] + bins[3][tid][1];
        float c  = bins[0][tid][2] + bins[1][tid][2] + bins[2][tid][2] + bins[3][tid][2];
        ws4[(size_t)tid * NSLOT + bid] = make_float4(s0, s1, c, 0.f);
    }
}

__global__ __launch_bounds__(256) void mlp_kernel(
    const float4* __restrict__ ws4,
    const float* __restrict__ Wc1, const float* __restrict__ bc1,
    const float* __restrict__ Wc2, const float* __restrict__ bc2,
    const float* __restrict__ Wc3, const float* __restrict__ bc3,
    float* __restrict__ out) {
    __shared__ float wred[4][8];  // per-wave partials of 7 values
    __shared__ float hgs[4];
    __shared__ float h1[128];
    __shared__ float part[2][128];
    __shared__ float h2[128];
    __shared__ float l3[16][12];  // 10 used, pad

    int g = blockIdx.x;
    int tid = threadIdx.x;

    // ---- Gather + reduce this graph's slots (coalesced 16 KB) ----
    float cs = 0.f, cc = 0.f, p0 = 0.f, p1 = 0.f, pc = 0.f, ns = 0.f, nc = 0.f;
    for (int s = tid; s < NSLOT; s += 256) {
        float4 v = ws4[(size_t)g * NSLOT + s];
        if (s < NB_COMP) { cs += v.x; cc += v.z; }
        else if (s < NB_COMP + NB_PORT) { p0 += v.x; p1 += v.y; pc += v.z; }
        else { ns += v.x; nc += v.z; }
    }
#pragma unroll
    for (int off = 32; off > 0; off >>= 1) {
        cs += __shfl_down(cs, off); cc += __shfl_down(cc, off);
        p0 += __shfl_down(p0, off); p1 += __shfl_down(p1, off);
        pc += __shfl_down(pc, off); ns += __shfl_down(ns, off);
        nc += __shfl_down(nc, off);
    }
    int wave = tid >> 6;
    if ((tid & 63) == 0) {
        wred[wave][0] = cs; wred[wave][1] = cc; wred[wave][2] = p0; wred[wave][3] = p1;
        wred[wave][4] = pc; wred[wave][5] = ns; wred[wave][6] = nc;
    }
    __syncthreads();
    if (tid == 0) {
        float t0 = wred[0][0] + wred[1][0] + wred[2][0] + wred[3][0];
        float t1 = wred[0][1] + wred[1][1] + wred[2][1] + wred[3][1];
        float t2 = wred[0][2] + wred[1][2] + wred[2][2] + wred[3][2];
        float t3 = wred[0][3] + wred[1][3] + wred[2][3] + wred[3][3];
        float t4 = wred[0][4] + wred[1][4] + wred[2][4] + wred[3][4];
        float t5 = wred[0][5] + wred[1][5] + wred[2][5] + wred[3][5];
        float t6 = wred[0][6] + wred[1][6] + wred[2][6] + wred[3][6];
        hgs[0] = t0 / fmaxf(t1, 1.f);
        hgs[1] = t2 / fmaxf(t4, 1.f);
        hgs[2] = t3 / fmaxf(t4, 1.f);
        hgs[3] = t5 / fmaxf(t6, 1.f);
    }
    __syncthreads();

    // ---- Layer 1: [4] @ [4,128] ----
    if (tid < 128) {
        float v = hgs[0] * Wc1[tid] + hgs[1] * Wc1[128 + tid] +
                  hgs[2] * Wc1[256 + tid] + hgs[3] * Wc1[384 + tid] + bc1[tid];
        h1[tid] = fmaxf(v, 0.f);
    }
    __syncthreads();

    // ---- Layer 2: [128] @ [128,128], split-k over 2 half-waves ----
    {
        int j = tid & 127;
        int h = tid >> 7;
        float acc = 0.f;
#pragma unroll
        for (int kk = 0; kk < 64; kk += 4) {
            int k = h * 64 + kk;
            float4 hh = *(const float4*)&h1[k];
            acc += hh.x * Wc2[(k + 0) * 128 + j] + hh.y * Wc2[(k + 1) * 128 + j] +
                   hh.z * Wc2[(k + 2) * 128 + j] + hh.w * Wc2[(k + 3) * 128 + j];
        }
        part[h][j] = acc;
    }
    __syncthreads();
    if (tid < 128) h2[tid] = fmaxf(part[0][tid] + part[1][tid] + bc2[tid], 0.f);
    __syncthreads();

    // ---- Layer 3: [128] @ [128,10], split-k over 16 segments of 8 ----
    if (tid < 160) {
        int c = tid % 10;
        int seg = tid / 10;
        float a = 0.f;
#pragma unroll
        for (int k = seg * 8; k < seg * 8 + 8; ++k) a += h2[k] * Wc3[k * 10 + c];
        l3[seg][c] = a;
    }
    __syncthreads();
    if (tid < 10) {
        float a = bc3[tid];
#pragma unroll
        for (int s = 0; s < 16; ++s) a += l3[s][tid];
        out[g * 10 + tid] = a;
    }
}

extern "C" void kernel_launch(void* const* d_in, const int* in_sizes, int n_in,
                              void* d_out, int out_size, void* d_ws, size_t ws_size,
                              hipStream_t stream) {
    const float* h_comp = (const float*)d_in[0];
    const float* h_port = (const float*)d_in[1];
    const float* h_net  = (const float*)d_in[2];
    // d_in[3..6]: edge arrays — dead code in the reference, unused.
    const int* gid_comp = (const int*)d_in[7];
    const int* gid_port = (const int*)d_in[8];
    const int* gid_net  = (const int*)d_in[9];
    // d_in[10..21]: GraphConv weights — dead code, unused.
    const float* Wc1 = (const float*)d_in[22];
    const float* bc1 = (const float*)d_in[23];
    const float* Wc2 = (const float*)d_in[24];
    const float* bc2 = (const float*)d_in[25];
    const float* Wc3 = (const float*)d_in[26];
    const float* bc3 = (const float*)d_in[27];

    int n_comp = in_sizes[0];       // 100000 (dim 1)
    int n_port = in_sizes[1] / 2;   // 400000 (dim 2)
    int n_net  = in_sizes[2];       // 150000 (dim 1)

    float4* ws4 = (float4*)d_ws;
    float* out = (float*)d_out;

    reduce_kernel<<<NSLOT, 256, 0, stream>>>(
        h_comp, h_port, h_net, gid_comp, gid_port, gid_net,
        n_comp, n_port, n_net, ws4);

    mlp_kernel<<<NGRAPH, 256, 0, stream>>>(ws4, Wc1, bc1, Wc2, bc2, Wc3, bc3, out);
}